// Round 2
// 174.784 us; speedup vs baseline: 1.0116x; 1.0116x over previous
//
#include <hip/hip_runtime.h>

typedef unsigned short ushort_t;
typedef __attribute__((ext_vector_type(8))) short short8;
typedef __attribute__((ext_vector_type(4))) float f32x4;

#define DIMC 512
#define PN   32768                  // 8*64*64 spatial positions
#define SQRTC 22.627416997969522f   // sqrt(512)

__device__ __forceinline__ ushort_t f2bf(float f) {
  unsigned int u = __float_as_uint(f);
  unsigned int r = u + 0x7fffu + ((u >> 16) & 1u);   // round-to-nearest-even
  return (ushort_t)(r >> 16);
}

// ---------------- cast wproj f32 -> bf16 [o][k] (k-contiguous)
__global__ __launch_bounds__(256) void k_cast(const float* __restrict__ a,
                                              ushort_t* __restrict__ b) {
  int i = (blockIdx.x * 256 + threadIdx.x) * 4;     // grid 256 -> 262144 el
  float4 v = *(const float4*)(a + i);
  ushort_t o[4] = {f2bf(v.x), f2bf(v.y), f2bf(v.z), f2bf(v.w)};
  *(uint2*)(b + i) = *(const uint2*)o;
}

// ---------------- WvT[c][k'] = bf16(wqkv[(1024+k')*512 + c])  (transpose V-weight)
__global__ __launch_bounds__(64) void k_wvt(const float* __restrict__ wqkv,
                                            ushort_t* __restrict__ WvT) {
  int c = blockIdx.x;          // 512
  int k8 = threadIdx.x * 8;    // 64 threads * 8 = 512
  ushort_t tmp[8];
#pragma unroll
  for (int j = 0; j < 8; ++j)
    tmp[j] = f2bf(wqkv[(long)(1024 + k8 + j) * DIMC + c]);  // scattered reads, 1MB footprint (L2)
  *(uint4*)(WvT + (long)c * DIMC + k8) = *(const uint4*)tmp;
}

// ---------------- fused bias: fb[o] = sum_k w_proj[o,k]*b_qkv[1024+k] + b_proj[o]
__global__ __launch_bounds__(256) void k_fb(const float* __restrict__ wp,
                                            const float* __restrict__ bqkv,
                                            const float* __restrict__ bproj,
                                            float* __restrict__ fb) {
  int wave = threadIdx.x >> 6;
  int lane = threadIdx.x & 63;
  int o = blockIdx.x * 4 + wave;          // grid 128 -> o in [0,512)
  float part = 0.f;
#pragma unroll
  for (int i = 0; i < 8; ++i) {
    int k = lane + i * 64;
    part += wp[o * DIMC + k] * bqkv[1024 + k];
  }
  for (int off = 32; off; off >>= 1) part += __shfl_down(part, off, 64);
  if (lane == 0) fb[o] = part + bproj[o];
}

// ---------------- small weight GEMM (m97-style, B^T input, both k-contiguous, K=512):
//   Mp[o][c] = bf16( (sum_k wpb[o,k] * WvT[c,k]) * gamma[c] )
__global__ __launch_bounds__(256) void k_gemm_w(
    const ushort_t* __restrict__ A,    // [512][512] bf16
    const ushort_t* __restrict__ BT,   // [512][512] bf16
    ushort_t* __restrict__ C,
    const float* __restrict__ gamma) {
  __shared__ ushort_t As[128 * 64];    // [row][64k], 16B-chunk XOR swizzle
  __shared__ ushort_t Bs[128 * 64];
  int tid = threadIdx.x;
  int p0 = blockIdx.x * 128;
  int o0 = blockIdx.y * 128;
  int wave = tid >> 6, lane = tid & 63;
  int wo = (wave & 1) * 64, wp = (wave >> 1) * 64;
  int q = lane >> 4, ln = lane & 15;

  f32x4 zero = {0.f, 0.f, 0.f, 0.f};
  f32x4 acc[4][4];
#pragma unroll
  for (int i = 0; i < 4; ++i)
#pragma unroll
    for (int j = 0; j < 4; ++j) acc[i][j] = zero;

  int sr = tid >> 3;                   // staging row 0..31 per sweep
  int sc = tid & 7;                    // 16B chunk 0..7
  const ushort_t* Ag = A + (long)(o0 + sr) * DIMC + sc * 8;
  const ushort_t* Bg = BT + (long)(p0 + sr) * DIMC + sc * 8;

  for (int kc = 0; kc < DIMC; kc += 64) {
    __syncthreads();
#pragma unroll
    for (int it = 0; it < 4; ++it) {
      int r = sr + it * 32;
      uint4 va = *(const uint4*)(Ag + (long)it * 32 * DIMC + kc);
      uint4 vb = *(const uint4*)(Bg + (long)it * 32 * DIMC + kc);
      int sw = ((sc ^ (r & 7)) * 8);
      *(uint4*)(&As[r * 64 + sw]) = va;
      *(uint4*)(&Bs[r * 64 + sw]) = vb;
    }
    __syncthreads();
#pragma unroll
    for (int ks = 0; ks < 2; ++ks) {
      int cch = ks * 4 + q;            // 16B chunk index 0..7
      short8 af[4], bf[4];
#pragma unroll
      for (int mi = 0; mi < 4; ++mi) {
        int row = wo + mi * 16 + ln;
        af[mi] = *(const short8*)(&As[row * 64 + ((cch ^ (row & 7)) * 8)]);
      }
#pragma unroll
      for (int ni = 0; ni < 4; ++ni) {
        int row = wp + ni * 16 + ln;
        bf[ni] = *(const short8*)(&Bs[row * 64 + ((cch ^ (row & 7)) * 8)]);
      }
#pragma unroll
      for (int mi = 0; mi < 4; ++mi)
#pragma unroll
        for (int ni = 0; ni < 4; ++ni)
          acc[mi][ni] = __builtin_amdgcn_mfma_f32_16x16x32_bf16(af[mi], bf[ni], acc[mi][ni], 0, 0, 0);
    }
  }

#pragma unroll
  for (int mi = 0; mi < 4; ++mi) {
    int obase = o0 + wo + mi * 16 + q * 4;
#pragma unroll
    for (int ni = 0; ni < 4; ++ni) {
      int p = p0 + wp + ni * 16 + ln;
      float g = gamma[p];
#pragma unroll
      for (int r = 0; r < 4; ++r)
        C[(long)(obase + r) * DIMC + p] = f2bf(acc[mi][ni][r] * g);
    }
  }
}

// ---------------- fused transpose + RMS-scale + main GEMM + residual epilogue.
// Block: 64 spatial positions (p), ALL 512 output channels. 512 threads = 8 waves.
//   stage:  xs[kb][p][64k-chunk-XOR] = bf16(x[k][p0+p]), one pass, reg 4x4 transpose;
//           ss[p] accumulated during cast -> s[p] = sqrt(512)/max(||x[:,p]||,1e-12)
//   K-loop: barrier-free. A-frags (Mp, L2-resident 512KB) direct from global;
//           B-frags from LDS (proven conflict-free chunk-XOR pattern).
//   epi:    out[o][p] = x[o][p] + fb[o] + s[p]*acc   (xid re-read is L2/L3-hot)
__global__ __launch_bounds__(512, 4) void k_fused(
    const float* __restrict__ x,
    const ushort_t* __restrict__ Mp,   // [512][512] bf16, k-contiguous
    const float* __restrict__ fb,
    float* __restrict__ out) {
  __shared__ ushort_t xs[8 * 64 * 64];   // 64 KB: [kb][p(64)][64k swizzled]
  __shared__ float red[32 * 65];         // 8.1 KB, stride 65 breaks write conflicts
  __shared__ float s_sh[64];
  int tid = threadIdx.x;
  long p0 = (long)blockIdx.x * 64;       // grid 512

  // ---- stage x -> xs (bf16, transposed, swizzled) + squared sums
  int pl4 = (tid & 15) * 4;              // local p 0,4,..,60 (fixed per thread)
  int kq  = tid >> 4;                    // 0..31
  float ss0 = 0.f, ss1 = 0.f, ss2 = 0.f, ss3 = 0.f;
#pragma unroll
  for (int sw = 0; sw < 4; ++sw) {
    int k4 = kq * 4 + sw * 128;          // 4 consecutive k rows per thread
    const float* xp = x + (long)k4 * PN + p0 + pl4;
    float4 v0 = *(const float4*)(xp);
    float4 v1 = *(const float4*)(xp + PN);
    float4 v2 = *(const float4*)(xp + 2 * PN);
    float4 v3 = *(const float4*)(xp + 3 * PN);
    ss0 += v0.x * v0.x + v1.x * v1.x + v2.x * v2.x + v3.x * v3.x;
    ss1 += v0.y * v0.y + v1.y * v1.y + v2.y * v2.y + v3.y * v3.y;
    ss2 += v0.z * v0.z + v1.z * v1.z + v2.z * v2.z + v3.z * v3.z;
    ss3 += v0.w * v0.w + v1.w * v1.w + v2.w * v2.w + v3.w * v3.w;
    // register 4x4 transpose -> 4x 8B LDS writes
    ushort_t t0[4] = {f2bf(v0.x), f2bf(v1.x), f2bf(v2.x), f2bf(v3.x)};
    ushort_t t1[4] = {f2bf(v0.y), f2bf(v1.y), f2bf(v2.y), f2bf(v3.y)};
    ushort_t t2[4] = {f2bf(v0.z), f2bf(v1.z), f2bf(v2.z), f2bf(v3.z)};
    ushort_t t3[4] = {f2bf(v0.w), f2bf(v1.w), f2bf(v2.w), f2bf(v3.w)};
    char* base = (char*)xs + (k4 >> 6) * 8192;
    int ch  = (k4 >> 3) & 7;             // 16B chunk within 64-k row
    int sub = (k4 & 7) * 2;              // byte offset within chunk (0 or 8)
    *(uint2*)(base + (pl4 + 0) * 128 + ((ch ^ ((pl4 + 0) & 7)) * 16) + sub) = *(const uint2*)t0;
    *(uint2*)(base + (pl4 + 1) * 128 + ((ch ^ ((pl4 + 1) & 7)) * 16) + sub) = *(const uint2*)t1;
    *(uint2*)(base + (pl4 + 2) * 128 + ((ch ^ ((pl4 + 2) & 7)) * 16) + sub) = *(const uint2*)t2;
    *(uint2*)(base + (pl4 + 3) * 128 + ((ch ^ ((pl4 + 3) & 7)) * 16) + sub) = *(const uint2*)t3;
  }
  red[kq * 65 + pl4 + 0] = ss0;
  red[kq * 65 + pl4 + 1] = ss1;
  red[kq * 65 + pl4 + 2] = ss2;
  red[kq * 65 + pl4 + 3] = ss3;
  __syncthreads();
  if (tid < 64) {
    float t = 0.f;
#pragma unroll
    for (int g = 0; g < 32; ++g) t += red[g * 65 + tid];
    s_sh[tid] = SQRTC / fmaxf(sqrtf(t), 1e-12f);
  }
  __syncthreads();

  // ---- barrier-free GEMM: wave w owns o in [64w, 64w+64), all 64 p
  int wave = tid >> 6, lane = tid & 63;
  int q = lane >> 4, ln = lane & 15;
  int wo = wave * 64;
  f32x4 zero = {0.f, 0.f, 0.f, 0.f};
  f32x4 acc[4][4];
#pragma unroll
  for (int i = 0; i < 4; ++i)
#pragma unroll
    for (int j = 0; j < 4; ++j) acc[i][j] = zero;

  const ushort_t* Ap = Mp + (long)wo * DIMC;   // wave's 64-row Mp slice
#pragma unroll 2
  for (int kb = 0; kb < 8; ++kb) {
    const char* bbase = (const char*)xs + kb * 8192;
#pragma unroll
    for (int ks = 0; ks < 2; ++ks) {
      int cch = ks * 4 + q;                    // 16B chunk 0..7 within kb
      int kk = kb * 64 + cch * 8;              // global k offset (ushorts)
      short8 af[4], bf[4];
#pragma unroll
      for (int mi = 0; mi < 4; ++mi)
        af[mi] = *(const short8*)(Ap + (long)(mi * 16 + ln) * DIMC + kk);
#pragma unroll
      for (int ni = 0; ni < 4; ++ni) {
        int row = ni * 16 + ln;
        bf[ni] = *(const short8*)(bbase + row * 128 + ((cch ^ (row & 7)) * 16));
      }
#pragma unroll
      for (int mi = 0; mi < 4; ++mi)
#pragma unroll
        for (int ni = 0; ni < 4; ++ni)
          acc[mi][ni] = __builtin_amdgcn_mfma_f32_16x16x32_bf16(af[mi], bf[ni], acc[mi][ni], 0, 0, 0);
    }
  }

  // ---- epilogue: residual + fused bias + RMS scale
#pragma unroll
  for (int mi = 0; mi < 4; ++mi) {
    int obase = wo + mi * 16 + q * 4;
#pragma unroll
    for (int ni = 0; ni < 4; ++ni) {
      int plocal = ni * 16 + ln;
      long p = p0 + plocal;
      float sv = s_sh[plocal];
#pragma unroll
      for (int r = 0; r < 4; ++r) {
        int o = obase + r;
        out[(long)o * PN + p] = x[(long)o * PN + p] + fb[o] + sv * acc[mi][ni][r];
      }
    }
  }
}

extern "C" void kernel_launch(void* const* d_in, const int* in_sizes, int n_in,
                              void* d_out, int out_size, void* d_ws, size_t ws_size,
                              hipStream_t stream) {
  const float* x     = (const float*)d_in[0];
  const float* gamma = (const float*)d_in[1];
  const float* wqkv  = (const float*)d_in[2];
  const float* bqkv  = (const float*)d_in[3];
  const float* wproj = (const float*)d_in[4];
  const float* bproj = (const float*)d_in[5];

  char* ws = (char*)d_ws;
  ushort_t* Mp  = (ushort_t*)(ws);             // 512*512 bf16  (524288 B)
  ushort_t* wpb = (ushort_t*)(ws + 524288);    // 512*512 bf16
  ushort_t* WvT = (ushort_t*)(ws + 1048576);   // 512*512 bf16
  float*    fb  = (float*)(ws + 1572864);      // 512 f32

  k_cast<<<dim3(256), dim3(256), 0, stream>>>(wproj, wpb);
  k_wvt<<<dim3(512), dim3(64), 0, stream>>>(wqkv, WvT);
  k_fb<<<dim3(128), dim3(256), 0, stream>>>(wproj, bqkv, bproj, fb);
  // Mp[o][c] = (sum_k wpb[o,k] * WvT[c,k]) * gamma[c]
  k_gemm_w<<<dim3(4, 4), dim3(256), 0, stream>>>(wpb, WvT, Mp, gamma);
  // out[o][p] = x[o][p] + fb[o] + s[p] * sum_c Mp[o,c]*bf16(x[c,p])
  k_fused<<<dim3(512), dim3(512), 0, stream>>>(x, Mp, fb, (float*)d_out);
}

// Round 4
// 163.648 us; speedup vs baseline: 1.0805x; 1.0680x over previous
//
#include <hip/hip_runtime.h>

typedef unsigned short ushort_t;
typedef __attribute__((ext_vector_type(8))) short short8;
typedef __attribute__((ext_vector_type(4))) float f32x4;

#define DIMC 512
#define PN   32768                  // 8*64*64 spatial positions
#define SQRTC 22.627416997969522f   // sqrt(512)

__device__ __forceinline__ ushort_t f2bf(float f) {
  unsigned int u = __float_as_uint(f);
  unsigned int r = u + 0x7fffu + ((u >> 16) & 1u);   // round-to-nearest-even
  return (ushort_t)(r >> 16);
}

// swizzle key: 2-way-max on BOTH stride-4-row writes and consecutive-row reads
__device__ __forceinline__ int kkey(int r) { return (r & 7) ^ ((r >> 2) & 7); }

// ---------------- fused prep: cast wproj, transpose V-weight, fused bias (1 launch)
__global__ __launch_bounds__(256) void k_prep(const float* __restrict__ wproj,
                                              const float* __restrict__ wqkv,
                                              const float* __restrict__ bqkv,
                                              const float* __restrict__ bproj,
                                              ushort_t* __restrict__ wpb,
                                              ushort_t* __restrict__ WvT,
                                              float* __restrict__ fb) {
  int bid = blockIdx.x, tid = threadIdx.x;
  if (bid < 256) {
    // cast wproj f32 -> bf16 [o][k]
    int i = (bid * 256 + tid) * 4;
    float4 v = *(const float4*)(wproj + i);
    ushort_t o[4] = {f2bf(v.x), f2bf(v.y), f2bf(v.z), f2bf(v.w)};
    *(uint2*)(wpb + i) = *(const uint2*)o;
  } else if (bid < 384) {
    // WvT[c][k'] = bf16(wqkv[(1024+k')*512 + c])
    int c = (bid - 256) * 4 + (tid >> 6);
    int k8 = (tid & 63) * 8;
    ushort_t tmp[8];
#pragma unroll
    for (int j = 0; j < 8; ++j)
      tmp[j] = f2bf(wqkv[(long)(1024 + k8 + j) * DIMC + c]);
    *(uint4*)(WvT + (long)c * DIMC + k8) = *(const uint4*)tmp;
  } else {
    // fb[o] = sum_k wproj[o,k]*bqkv[1024+k] + bproj[o]
    int wave = tid >> 6, lane = tid & 63;
    int o = (bid - 384) * 4 + wave;
    float part = 0.f;
#pragma unroll
    for (int i = 0; i < 8; ++i) {
      int k = lane + i * 64;
      part += wproj[o * DIMC + k] * bqkv[1024 + k];
    }
    for (int off = 32; off; off >>= 1) part += __shfl_down(part, off, 64);
    if (lane == 0) fb[o] = part + bproj[o];
  }
}

// ---------------- small weight GEMM (K=512):
//   Mp2 = pre-fragmented ( (sum_k wpb[o,k] * WvT[c,k]) * gamma[c] )
// Output layout: idx(o,c) = ((((w*8+kb)*2+ks)*4+mi)*64 + q*16+ln)*8 + j
//   w=o>>6, mi=(o>>4)&3, ln=o&15, kb=c>>6, ks=(c>>5)&1, q=(c>>3)&3, j=c&7
// so the main kernel's A-fragment loads are lane-contiguous (coalesced 1KB).
__global__ __launch_bounds__(256) void k_gemm_w(
    const ushort_t* __restrict__ A,    // [512][512] bf16  (wpb)
    const ushort_t* __restrict__ BT,   // [512][512] bf16  (WvT)
    ushort_t* __restrict__ C,          // Mp2, fragment layout
    const float* __restrict__ gamma) {
  __shared__ ushort_t As[128 * 64];
  __shared__ ushort_t Bs[128 * 64];
  int tid = threadIdx.x;
  int p0 = blockIdx.x * 128;           // c-range
  int o0 = blockIdx.y * 128;           // o-range
  int wave = tid >> 6, lane = tid & 63;
  int wo = (wave & 1) * 64, wp = (wave >> 1) * 64;
  int q = lane >> 4, ln = lane & 15;

  f32x4 zero = {0.f, 0.f, 0.f, 0.f};
  f32x4 acc[4][4];
#pragma unroll
  for (int i = 0; i < 4; ++i)
#pragma unroll
    for (int j = 0; j < 4; ++j) acc[i][j] = zero;

  int sr = tid >> 3;
  int sc = tid & 7;
  const ushort_t* Ag = A + (long)(o0 + sr) * DIMC + sc * 8;
  const ushort_t* Bg = BT + (long)(p0 + sr) * DIMC + sc * 8;

  for (int kc = 0; kc < DIMC; kc += 64) {
    __syncthreads();
#pragma unroll
    for (int it = 0; it < 4; ++it) {
      int r = sr + it * 32;
      uint4 va = *(const uint4*)(Ag + (long)it * 32 * DIMC + kc);
      uint4 vb = *(const uint4*)(Bg + (long)it * 32 * DIMC + kc);
      int sw = ((sc ^ (r & 7)) * 8);
      *(uint4*)(&As[r * 64 + sw]) = va;
      *(uint4*)(&Bs[r * 64 + sw]) = vb;
    }
    __syncthreads();
#pragma unroll
    for (int ks = 0; ks < 2; ++ks) {
      int cch = ks * 4 + q;
      short8 af[4], bf[4];
#pragma unroll
      for (int mi = 0; mi < 4; ++mi) {
        int row = wo + mi * 16 + ln;
        af[mi] = *(const short8*)(&As[row * 64 + ((cch ^ (row & 7)) * 8)]);
      }
#pragma unroll
      for (int ni = 0; ni < 4; ++ni) {
        int row = wp + ni * 16 + ln;
        bf[ni] = *(const short8*)(&Bs[row * 64 + ((cch ^ (row & 7)) * 8)]);
      }
#pragma unroll
      for (int mi = 0; mi < 4; ++mi)
#pragma unroll
        for (int ni = 0; ni < 4; ++ni)
          acc[mi][ni] = __builtin_amdgcn_mfma_f32_16x16x32_bf16(af[mi], bf[ni], acc[mi][ni], 0, 0, 0);
    }
  }

#pragma unroll
  for (int mi = 0; mi < 4; ++mi) {
    int obase = o0 + wo + mi * 16 + q * 4;
#pragma unroll
    for (int ni = 0; ni < 4; ++ni) {
      int c = p0 + wp + ni * 16 + ln;
      float g = gamma[c];
      int kb2 = c >> 6, ks2 = (c >> 5) & 1, q2 = (c >> 3) & 3, j2 = c & 7;
#pragma unroll
      for (int r = 0; r < 4; ++r) {
        int o = obase + r;
        int w2 = o >> 6, mi2 = (o >> 4) & 3, ln2 = o & 15;
        long idx = (((((long)w2 * 8 + kb2) * 2 + ks2) * 4 + mi2) * 64 + q2 * 16 + ln2) * 8 + j2;
        C[idx] = f2bf(acc[mi][ni][r] * g);
      }
    }
  }
}

// ---------------- fused transpose + RMS-scale + main GEMM + residual epilogue.
// Block: 64 spatial positions (p), ALL 512 output channels. 512 threads = 8 waves.
//   stage:  xs[kb][p][64k swizzled] = bf16(x[k][p0+p]); ss accumulated -> s[p]
//   K-loop: barrier-free; A-frags COALESCED from fragment-layout Mp2 (L2-hot),
//           kb=0 frags prefetched before staging; B-frags from LDS (2-way max).
//   epi:    out[o][p] = x[o][p] + fb[o] + s[p]*acc   (x re-read is L2-hot)
__global__ __launch_bounds__(512, 4) void k_fused(
    const float* __restrict__ x,
    const ushort_t* __restrict__ Mp2,  // fragment layout, 512KB
    const float* __restrict__ fb,
    float* __restrict__ out) {
  __shared__ ushort_t xs[8 * 64 * 64];   // 64 KB: [kb][p(64)][64k swizzled]
  __shared__ float red[32 * 65];
  __shared__ float s_sh[64];
  int tid = threadIdx.x;
  long p0 = (long)blockIdx.x * 64;       // grid 512

  int wave = tid >> 6, lane = tid & 63;
  int q = lane >> 4, ln = lane & 15;

  // ---- prefetch kb=0 A-fragments (coalesced, in flight during staging)
  const ushort_t* Aw = Mp2 + (long)wave * 32768 + lane * 8;
  short8 a0[8];
#pragma unroll
  for (int f = 0; f < 8; ++f) a0[f] = *(const short8*)(Aw + f * 512);

  // ---- stage x -> xs (bf16, transposed, swizzled) + squared sums
  int pl4 = (tid & 15) * 4;              // local p 0,4,..,60
  int kq  = tid >> 4;                    // 0..31
  float ss0 = 0.f, ss1 = 0.f, ss2 = 0.f, ss3 = 0.f;
#pragma unroll
  for (int sw = 0; sw < 4; ++sw) {
    int k4 = kq * 4 + sw * 128;          // 4 consecutive k rows per thread
    const float* xp = x + (long)k4 * PN + p0 + pl4;
    float4 v0 = *(const float4*)(xp);
    float4 v1 = *(const float4*)(xp + PN);
    float4 v2 = *(const float4*)(xp + 2 * PN);
    float4 v3 = *(const float4*)(xp + 3 * PN);
    ss0 += v0.x * v0.x + v1.x * v1.x + v2.x * v2.x + v3.x * v3.x;
    ss1 += v0.y * v0.y + v1.y * v1.y + v2.y * v2.y + v3.y * v3.y;
    ss2 += v0.z * v0.z + v1.z * v1.z + v2.z * v2.z + v3.z * v3.z;
    ss3 += v0.w * v0.w + v1.w * v1.w + v2.w * v2.w + v3.w * v3.w;
    ushort_t t0[4] = {f2bf(v0.x), f2bf(v1.x), f2bf(v2.x), f2bf(v3.x)};
    ushort_t t1[4] = {f2bf(v0.y), f2bf(v1.y), f2bf(v2.y), f2bf(v3.y)};
    ushort_t t2[4] = {f2bf(v0.z), f2bf(v1.z), f2bf(v2.z), f2bf(v3.z)};
    ushort_t t3[4] = {f2bf(v0.w), f2bf(v1.w), f2bf(v2.w), f2bf(v3.w)};
    char* base = (char*)xs + (k4 >> 6) * 8192;
    int ch  = (k4 >> 3) & 7;             // 16B chunk within 64-k row
    int sub = (k4 & 7) * 2;              // byte offset within chunk (0 or 8)
    *(uint2*)(base + (pl4 + 0) * 128 + ((ch ^ kkey(pl4 + 0)) * 16) + sub) = *(const uint2*)t0;
    *(uint2*)(base + (pl4 + 1) * 128 + ((ch ^ kkey(pl4 + 1)) * 16) + sub) = *(const uint2*)t1;
    *(uint2*)(base + (pl4 + 2) * 128 + ((ch ^ kkey(pl4 + 2)) * 16) + sub) = *(const uint2*)t2;
    *(uint2*)(base + (pl4 + 3) * 128 + ((ch ^ kkey(pl4 + 3)) * 16) + sub) = *(const uint2*)t3;
  }
  red[kq * 65 + pl4 + 0] = ss0;
  red[kq * 65 + pl4 + 1] = ss1;
  red[kq * 65 + pl4 + 2] = ss2;
  red[kq * 65 + pl4 + 3] = ss3;
  __syncthreads();
  if (tid < 64) {
    float t = 0.f;
#pragma unroll
    for (int g = 0; g < 32; ++g) t += red[g * 65 + tid];
    s_sh[tid] = SQRTC / fmaxf(sqrtf(t), 1e-12f);
  }
  __syncthreads();

  // ---- barrier-free GEMM: wave w owns o in [64w, 64w+64), all 64 p
  f32x4 zero = {0.f, 0.f, 0.f, 0.f};
  f32x4 acc[4][4];
#pragma unroll
  for (int i = 0; i < 4; ++i)
#pragma unroll
    for (int j = 0; j < 4; ++j) acc[i][j] = zero;

#pragma unroll
  for (int kb = 0; kb < 8; ++kb) {
    const char* bbase = (const char*)xs + kb * 8192;
#pragma unroll
    for (int ks = 0; ks < 2; ++ks) {
      short8 af[4], bf[4];
#pragma unroll
      for (int mi = 0; mi < 4; ++mi)
        af[mi] = (kb == 0) ? a0[ks * 4 + mi]
                           : *(const short8*)(Aw + ((kb * 2 + ks) * 4 + mi) * 512);
      int cch = ks * 4 + q;
#pragma unroll
      for (int ni = 0; ni < 4; ++ni) {
        int row = ni * 16 + ln;
        bf[ni] = *(const short8*)(bbase + row * 128 + ((cch ^ kkey(row)) * 16));
      }
#pragma unroll
      for (int mi = 0; mi < 4; ++mi)
#pragma unroll
        for (int ni = 0; ni < 4; ++ni)
          acc[mi][ni] = __builtin_amdgcn_mfma_f32_16x16x32_bf16(af[mi], bf[ni], acc[mi][ni], 0, 0, 0);
    }
  }

  // ---- epilogue: residual + fused bias + RMS scale
  int wo = wave * 64;
#pragma unroll
  for (int mi = 0; mi < 4; ++mi) {
    int obase = wo + mi * 16 + q * 4;
#pragma unroll
    for (int ni = 0; ni < 4; ++ni) {
      int plocal = ni * 16 + ln;
      long p = p0 + plocal;
      float sv = s_sh[plocal];
#pragma unroll
      for (int r = 0; r < 4; ++r) {
        int o = obase + r;
        out[(long)o * PN + p] = x[(long)o * PN + p] + fb[o] + sv * acc[mi][ni][r];
      }
    }
  }
}

extern "C" void kernel_launch(void* const* d_in, const int* in_sizes, int n_in,
                              void* d_out, int out_size, void* d_ws, size_t ws_size,
                              hipStream_t stream) {
  const float* x     = (const float*)d_in[0];
  const float* gamma = (const float*)d_in[1];
  const float* wqkv  = (const float*)d_in[2];
  const float* bqkv  = (const float*)d_in[3];
  const float* wproj = (const float*)d_in[4];
  const float* bproj = (const float*)d_in[5];

  char* ws = (char*)d_ws;
  ushort_t* Mp2 = (ushort_t*)(ws);             // 512*512 bf16 fragment layout (524288 B)
  ushort_t* wpb = (ushort_t*)(ws + 524288);    // 512*512 bf16
  ushort_t* WvT = (ushort_t*)(ws + 1048576);   // 512*512 bf16
  float*    fb  = (float*)(ws + 1572864);      // 512 f32

  k_prep<<<dim3(512), dim3(256), 0, stream>>>(wproj, wqkv, bqkv, bproj, wpb, WvT, fb);
  // Mp2(frag layout) = (wpb @ WvT^T) * gamma
  k_gemm_w<<<dim3(4, 4), dim3(256), 0, stream>>>(wpb, WvT, Mp2, gamma);
  // out[o][p] = x[o][p] + fb[o] + s[p] * sum_c Mp[o,c]*bf16(x[c,p])
  k_fused<<<dim3(512), dim3(512), 0, stream>>>(x, Mp2, fb, (float*)d_out);
}